// Round 1
// baseline (2315.059 us; speedup 1.0000x reference)
//
#include <hip/hip_runtime.h>

// Problem: SNN classifier.
//   x  [B=128, T=25, C*H*W=F=12288] f32
//   W1 [HID=2048, F] f32, b1 [HID]
//   Wo [O=2, HID] f32, bo [O]
// h_all[t,b,h] = sum_f x[b,t,f]*W1[h,f] + b1[h]   (161 GFLOP fp32 GEMM)
// then sequential LIF scan over T, output = sum_t spike_out  -> [B, O] f32.

#define T_STEPS 25
#define B_SZ    128
#define F_SZ    12288
#define HID_SZ  2048

// ---------------- GEMM: h_all[3200, 2048] = A[3200, 12288] @ W1^T + b1 -----
// A row m = t*128 + b  reads x[b][t][:]. Both A and W1 are K-contiguous (NT).
// 128x128 block tile, 8x8 micro-tile, BK=16, 256 threads.
__global__ __launch_bounds__(256) void gemm_h_kernel(
    const float* __restrict__ x, const float* __restrict__ W1,
    const float* __restrict__ b1, float* __restrict__ h_all) {
  __shared__ float As[16][128];
  __shared__ float Bs[16][128];
  const int tid = threadIdx.x;
  const int tx = tid & 15;   // N micro index
  const int ty = tid >> 4;   // M micro index
  const int m0 = blockIdx.x * 128;
  const int n0 = blockIdx.y * 128;

  // staging assignment: each thread loads 8 floats (2x float4) of one row
  const int lrow = tid >> 1;        // 0..127
  const int lcol = (tid & 1) * 8;   // 0 or 8

  const int gm = m0 + lrow;
  const int bb = gm & (B_SZ - 1);   // b
  const int tt = gm >> 7;           // t
  const float* aptr = x + ((size_t)bb * T_STEPS + tt) * F_SZ + lcol;
  const float* bptr = W1 + (size_t)(n0 + lrow) * F_SZ + lcol;

  float acc[8][8];
#pragma unroll
  for (int i = 0; i < 8; ++i)
#pragma unroll
    for (int j = 0; j < 8; ++j) acc[i][j] = 0.f;

  for (int k0 = 0; k0 < F_SZ; k0 += 16) {
    float4 av0 = *(const float4*)(aptr + k0);
    float4 av1 = *(const float4*)(aptr + k0 + 4);
    float4 bv0 = *(const float4*)(bptr + k0);
    float4 bv1 = *(const float4*)(bptr + k0 + 4);
    As[lcol + 0][lrow] = av0.x;
    As[lcol + 1][lrow] = av0.y;
    As[lcol + 2][lrow] = av0.z;
    As[lcol + 3][lrow] = av0.w;
    As[lcol + 4][lrow] = av1.x;
    As[lcol + 5][lrow] = av1.y;
    As[lcol + 6][lrow] = av1.z;
    As[lcol + 7][lrow] = av1.w;
    Bs[lcol + 0][lrow] = bv0.x;
    Bs[lcol + 1][lrow] = bv0.y;
    Bs[lcol + 2][lrow] = bv0.z;
    Bs[lcol + 3][lrow] = bv0.w;
    Bs[lcol + 4][lrow] = bv1.x;
    Bs[lcol + 5][lrow] = bv1.y;
    Bs[lcol + 6][lrow] = bv1.z;
    Bs[lcol + 7][lrow] = bv1.w;
    __syncthreads();
#pragma unroll
    for (int k = 0; k < 16; ++k) {
      float4 a0 = *(const float4*)&As[k][ty * 8];
      float4 a1 = *(const float4*)&As[k][ty * 8 + 4];
      float4 q0 = *(const float4*)&Bs[k][tx * 8];
      float4 q1 = *(const float4*)&Bs[k][tx * 8 + 4];
      float ar[8] = {a0.x, a0.y, a0.z, a0.w, a1.x, a1.y, a1.z, a1.w};
      float br[8] = {q0.x, q0.y, q0.z, q0.w, q1.x, q1.y, q1.z, q1.w};
#pragma unroll
      for (int i = 0; i < 8; ++i)
#pragma unroll
        for (int j = 0; j < 8; ++j)
          acc[i][j] = fmaf(ar[i], br[j], acc[i][j]);
    }
    __syncthreads();
  }

  // epilogue: add bias, store h_all
#pragma unroll
  for (int i = 0; i < 8; ++i) {
    const int gm2 = m0 + ty * 8 + i;
    float* orow = h_all + (size_t)gm2 * HID_SZ + n0 + tx * 8;
    const float* brow = b1 + n0 + tx * 8;
    float4 o0, o1;
    o0.x = acc[i][0] + brow[0];
    o0.y = acc[i][1] + brow[1];
    o0.z = acc[i][2] + brow[2];
    o0.w = acc[i][3] + brow[3];
    o1.x = acc[i][4] + brow[4];
    o1.y = acc[i][5] + brow[5];
    o1.z = acc[i][6] + brow[6];
    o1.w = acc[i][7] + brow[7];
    *(float4*)orow = o0;
    *(float4*)(orow + 4) = o1;
  }
}

// ---------------- LIF scan over T ------------------------------------------
// One block per batch element b. 256 threads; thread owns 8 hidden units
// h = tid + 256*i (coalesced). mem1 in registers; Wo columns in registers.
// Per step: update mem1, spike, reduce s1 @ Wo^T (2 outputs) across block,
// thread 0 evolves output-layer membrane and accumulates spikes.
__global__ __launch_bounds__(256) void lif_scan_kernel(
    const float* __restrict__ h_all, const float* __restrict__ Wo,
    const float* __restrict__ bo, float* __restrict__ out) {
  const int b = blockIdx.x;
  const int tid = threadIdx.x;

  float mem1[8];
  float wo0[8], wo1[8];
#pragma unroll
  for (int i = 0; i < 8; ++i) {
    mem1[i] = 0.f;
    wo0[i] = Wo[tid + 256 * i];
    wo1[i] = Wo[HID_SZ + tid + 256 * i];
  }

  __shared__ float partial[4][2];
  float memo0 = 0.f, memo1 = 0.f, acc0 = 0.f, acc1 = 0.f;
  const float bo0 = bo[0], bo1 = bo[1];

  for (int t = 0; t < T_STEPS; ++t) {
    const float* hrow = h_all + ((size_t)t * B_SZ + b) * HID_SZ;
    float p0 = 0.f, p1 = 0.f;
#pragma unroll
    for (int i = 0; i < 8; ++i) {
      float h = hrow[tid + 256 * i];
      float r1 = mem1[i] > 1.0f ? 1.0f : 0.0f;           // reset from prev mem
      float m = 0.9f * mem1[i] + h - r1;                 // THR = 1
      mem1[i] = m;
      if (m > 1.0f) { p0 += wo0[i]; p1 += wo1[i]; }      // s1 * Wo
    }
    // wave64 reduce
#pragma unroll
    for (int off = 32; off > 0; off >>= 1) {
      p0 += __shfl_down(p0, off);
      p1 += __shfl_down(p1, off);
    }
    const int wave = tid >> 6;
    if ((tid & 63) == 0) { partial[wave][0] = p0; partial[wave][1] = p1; }
    __syncthreads();
    if (tid == 0) {
      float o0 = partial[0][0] + partial[1][0] + partial[2][0] + partial[3][0] + bo0;
      float o1 = partial[0][1] + partial[1][1] + partial[2][1] + partial[3][1] + bo1;
      float ro0 = memo0 > 1.0f ? 1.0f : 0.0f;
      float ro1 = memo1 > 1.0f ? 1.0f : 0.0f;
      memo0 = 0.9f * memo0 + o0 - ro0;
      memo1 = 0.9f * memo1 + o1 - ro1;
      acc0 += memo0 > 1.0f ? 1.0f : 0.0f;
      acc1 += memo1 > 1.0f ? 1.0f : 0.0f;
    }
    __syncthreads();  // protect partial[] before next step's writes
  }
  if (tid == 0) {
    out[b * 2 + 0] = acc0;
    out[b * 2 + 1] = acc1;
  }
}

extern "C" void kernel_launch(void* const* d_in, const int* in_sizes, int n_in,
                              void* d_out, int out_size, void* d_ws, size_t ws_size,
                              hipStream_t stream) {
  const float* x  = (const float*)d_in[0];
  const float* W1 = (const float*)d_in[1];
  const float* b1 = (const float*)d_in[2];
  const float* Wo = (const float*)d_in[3];
  const float* bo = (const float*)d_in[4];
  float* out = (float*)d_out;
  float* h_all = (float*)d_ws;  // 3200 * 2048 * 4 = 26.2 MB

  dim3 grid(25, 16);  // M=3200/128, N=2048/128
  gemm_h_kernel<<<grid, 256, 0, stream>>>(x, W1, b1, h_all);
  lif_scan_kernel<<<B_SZ, 256, 0, stream>>>(h_all, Wo, bo, out);
}

// Round 2
// 634.346 us; speedup vs baseline: 3.6495x; 3.6495x over previous
//
#include <hip/hip_runtime.h>

// SNN classifier: h_all = x @ W1^T + b1 (fp32-accurate via f16 split-2 MFMA),
// then sequential LIF scan over T=25 steps.
//   x  [B=128, T=25, F=12288] f32 ; W1 [2048, 12288] ; Wo [2,2048]
// Split: x = Ah+Al (f16), W*128 = Bh+Bl (f16); h*128 = AhBh + AhBl + AlBh.
// A2/B2 are pre-swizzled LDS images: per 128-row x 32-k chunk, each row is
// 128B = 8 slots of 16B: slots 0-3 hi(k0..31), 4-7 lo(k0..31), slot index
// XORed with (row&7)  -> conflict-lite ds_read_b128 fragment loads.

#define T_STEPS 25
#define B_SZ    128
#define F_SZ    12288
#define HID_SZ  2048
#define KSTEPS  384          // F / 32
#define CHUNK   16384        // 128 rows * 128 bytes

typedef __attribute__((ext_vector_type(8))) _Float16 f16x8;
typedef __attribute__((ext_vector_type(4))) float f32x4;

__device__ __forceinline__ void g2l16(const void* g, void* l) {
  __builtin_amdgcn_global_load_lds(
      (const __attribute__((address_space(1))) void*)g,
      (__attribute__((address_space(3))) void*)l, 16, 0, 0);
}

// ---- conversion: x -> A2 [t][ks][r=b][128B swizzled row] -------------------
__global__ __launch_bounds__(256) void conv_x_kernel(
    const float* __restrict__ x, char* __restrict__ A2) {
  const int total = T_STEPS * KSTEPS * 128 * 4;  // (t,ks,r,s)
  for (int i = blockIdx.x * 256 + threadIdx.x; i < total; i += gridDim.x * 256) {
    const int s = i & 3;
    const int r = (i >> 2) & 127;
    const int rest = i >> 9;              // t*KSTEPS + ks
    const int ks = rest % KSTEPS;
    const int t = rest / KSTEPS;
    const int k0 = ks * 32 + s * 8;
    const float* src = x + ((size_t)r * T_STEPS + t) * F_SZ + k0;  // r = b
    float4 v0 = *(const float4*)src;
    float4 v1 = *(const float4*)(src + 4);
    float vf[8] = {v0.x, v0.y, v0.z, v0.w, v1.x, v1.y, v1.z, v1.w};
    f16x8 hi, lo;
#pragma unroll
    for (int j = 0; j < 8; ++j) {
      _Float16 h = (_Float16)vf[j];
      hi[j] = h;
      lo[j] = (_Float16)(vf[j] - (float)h);
    }
    char* chunk = A2 + (size_t)rest * CHUNK;
    const int p = s ^ (r & 7);
    *(f16x8*)(chunk + r * 128 + p * 16) = hi;
    *(f16x8*)(chunk + r * 128 + (p ^ 4) * 16) = lo;
  }
}

// ---- conversion: W1*128 -> B2 [nt][ks][r=n%128][swizzled row] --------------
__global__ __launch_bounds__(256) void conv_w_kernel(
    const float* __restrict__ W1, char* __restrict__ B2) {
  const int total = 16 * KSTEPS * 128 * 4;
  for (int i = blockIdx.x * 256 + threadIdx.x; i < total; i += gridDim.x * 256) {
    const int s = i & 3;
    const int r = (i >> 2) & 127;
    const int rest = i >> 9;              // nt*KSTEPS + ks
    const int ks = rest % KSTEPS;
    const int nt = rest / KSTEPS;
    const int k0 = ks * 32 + s * 8;
    const float* src = W1 + ((size_t)(nt * 128 + r)) * F_SZ + k0;
    float4 v0 = *(const float4*)src;
    float4 v1 = *(const float4*)(src + 4);
    float vf[8] = {v0.x, v0.y, v0.z, v0.w, v1.x, v1.y, v1.z, v1.w};
    f16x8 hi, lo;
#pragma unroll
    for (int j = 0; j < 8; ++j) {
      float vs = vf[j] * 128.0f;          // scale keeps residual normal-range
      _Float16 h = (_Float16)vs;
      hi[j] = h;
      lo[j] = (_Float16)(vs - (float)h);
    }
    char* chunk = B2 + (size_t)rest * CHUNK;
    const int p = s ^ (r & 7);
    *(f16x8*)(chunk + r * 128 + p * 16) = hi;
    *(f16x8*)(chunk + r * 128 + (p ^ 4) * 16) = lo;
  }
}

// ---- MFMA GEMM: 128x128 tile, 4 waves (2x2), 4x4 frags/wave, BK=32 ---------
__global__ __launch_bounds__(256, 2) void gemm_split_kernel(
    const char* __restrict__ A2, const char* __restrict__ B2,
    const float* __restrict__ b1, float* __restrict__ h_all) {
  __shared__ __align__(16) char lds[32768];  // A tile 16KB | B tile 16KB
  const int tid = threadIdx.x;
  const int l = tid & 63;
  const int w = tid >> 6;
  const int wm = w >> 1, wn = w & 1;

  // XCD-aware swizzle: 400 blocks = 8 XCDs * 50; n-tile fastest within XCD.
  const int bid = blockIdx.x;
  const int swz = (bid & 7) * 50 + (bid >> 3);
  const int mt = swz >> 4;   // 0..24
  const int nt = swz & 15;   // 0..15
  const char* aSrc = A2 + (size_t)mt * KSTEPS * CHUNK;
  const char* bSrc = B2 + (size_t)nt * KSTEPS * CHUNK;

  f32x4 acc[4][4];
#pragma unroll
  for (int i = 0; i < 4; ++i)
#pragma unroll
    for (int j = 0; j < 4; ++j) acc[i][j] = (f32x4){0.f, 0.f, 0.f, 0.f};

  const int ra = wm * 64 + (l & 15);
  const int rb = wn * 64 + (l & 15);
  const int j4 = l >> 4;  // k-slot 0..3

  for (int k = 0; k < KSTEPS; ++k) {
    const char* ga = aSrc + (size_t)k * CHUNK + tid * 16;
    const char* gb = bSrc + (size_t)k * CHUNK + tid * 16;
    char* la = lds + w * 1024;
    char* lb = lds + 16384 + w * 1024;
#pragma unroll
    for (int i = 0; i < 4; ++i) g2l16(ga + i * 4096, la + i * 4096);
#pragma unroll
    for (int i = 0; i < 4; ++i) g2l16(gb + i * 4096, lb + i * 4096);
    __syncthreads();  // drains vmcnt before barrier

    f16x8 ah[4], al[4], bh[4], bl[4];
#pragma unroll
    for (int mb = 0; mb < 4; ++mb) {
      const int r = ra + mb * 16;
      const char* base = lds + r * 128;
      ah[mb] = *(const f16x8*)(base + ((j4 ^ (r & 7)) << 4));
      al[mb] = *(const f16x8*)(base + (((j4 | 4) ^ (r & 7)) << 4));
    }
#pragma unroll
    for (int nb = 0; nb < 4; ++nb) {
      const int r = rb + nb * 16;
      const char* base = lds + 16384 + r * 128;
      bh[nb] = *(const f16x8*)(base + ((j4 ^ (r & 7)) << 4));
      bl[nb] = *(const f16x8*)(base + (((j4 | 4) ^ (r & 7)) << 4));
    }
#pragma unroll
    for (int mb = 0; mb < 4; ++mb)
#pragma unroll
      for (int nb = 0; nb < 4; ++nb) {
        acc[mb][nb] = __builtin_amdgcn_mfma_f32_16x16x32_f16(ah[mb], bh[nb], acc[mb][nb], 0, 0, 0);
        acc[mb][nb] = __builtin_amdgcn_mfma_f32_16x16x32_f16(ah[mb], bl[nb], acc[mb][nb], 0, 0, 0);
        acc[mb][nb] = __builtin_amdgcn_mfma_f32_16x16x32_f16(al[mb], bh[nb], acc[mb][nb], 0, 0, 0);
      }
    __syncthreads();
  }

  // epilogue: h = acc/128 + b1.  C/D frag: col = lane&15, row = (lane>>4)*4+q
  const int m0 = mt * 128 + wm * 64;
  const int n0 = nt * 128 + wn * 64;
  const int row_l = (l >> 4) * 4;
  const int col_l = l & 15;
#pragma unroll
  for (int nb = 0; nb < 4; ++nb) {
    const int col = n0 + nb * 16 + col_l;
    const float bias = b1[col];
#pragma unroll
    for (int mb = 0; mb < 4; ++mb) {
#pragma unroll
      for (int q = 0; q < 4; ++q) {
        const int row = m0 + mb * 16 + row_l + q;
        h_all[(size_t)row * HID_SZ + col] = acc[mb][nb][q] * 0.0078125f + bias;
      }
    }
  }
}

// ---- fallback fp32 vector GEMM (round-1, used only if ws too small) --------
__global__ __launch_bounds__(256) void gemm_h_kernel(
    const float* __restrict__ x, const float* __restrict__ W1,
    const float* __restrict__ b1, float* __restrict__ h_all) {
  __shared__ float As[16][128];
  __shared__ float Bs[16][128];
  const int tid = threadIdx.x;
  const int tx = tid & 15;
  const int ty = tid >> 4;
  const int m0 = blockIdx.x * 128;
  const int n0 = blockIdx.y * 128;
  const int lrow = tid >> 1;
  const int lcol = (tid & 1) * 8;
  const int gm = m0 + lrow;
  const int bb = gm & (B_SZ - 1);
  const int tt = gm >> 7;
  const float* aptr = x + ((size_t)bb * T_STEPS + tt) * F_SZ + lcol;
  const float* bptr = W1 + (size_t)(n0 + lrow) * F_SZ + lcol;
  float acc[8][8];
#pragma unroll
  for (int i = 0; i < 8; ++i)
#pragma unroll
    for (int j = 0; j < 8; ++j) acc[i][j] = 0.f;
  for (int k0 = 0; k0 < F_SZ; k0 += 16) {
    float4 av0 = *(const float4*)(aptr + k0);
    float4 av1 = *(const float4*)(aptr + k0 + 4);
    float4 bv0 = *(const float4*)(bptr + k0);
    float4 bv1 = *(const float4*)(bptr + k0 + 4);
    As[lcol + 0][lrow] = av0.x; As[lcol + 1][lrow] = av0.y;
    As[lcol + 2][lrow] = av0.z; As[lcol + 3][lrow] = av0.w;
    As[lcol + 4][lrow] = av1.x; As[lcol + 5][lrow] = av1.y;
    As[lcol + 6][lrow] = av1.z; As[lcol + 7][lrow] = av1.w;
    Bs[lcol + 0][lrow] = bv0.x; Bs[lcol + 1][lrow] = bv0.y;
    Bs[lcol + 2][lrow] = bv0.z; Bs[lcol + 3][lrow] = bv0.w;
    Bs[lcol + 4][lrow] = bv1.x; Bs[lcol + 5][lrow] = bv1.y;
    Bs[lcol + 6][lrow] = bv1.z; Bs[lcol + 7][lrow] = bv1.w;
    __syncthreads();
#pragma unroll
    for (int k = 0; k < 16; ++k) {
      float4 a0 = *(const float4*)&As[k][ty * 8];
      float4 a1 = *(const float4*)&As[k][ty * 8 + 4];
      float4 q0 = *(const float4*)&Bs[k][tx * 8];
      float4 q1 = *(const float4*)&Bs[k][tx * 8 + 4];
      float ar[8] = {a0.x, a0.y, a0.z, a0.w, a1.x, a1.y, a1.z, a1.w};
      float br[8] = {q0.x, q0.y, q0.z, q0.w, q1.x, q1.y, q1.z, q1.w};
#pragma unroll
      for (int i = 0; i < 8; ++i)
#pragma unroll
        for (int j = 0; j < 8; ++j)
          acc[i][j] = fmaf(ar[i], br[j], acc[i][j]);
    }
    __syncthreads();
  }
#pragma unroll
  for (int i = 0; i < 8; ++i) {
    const int gm2 = m0 + ty * 8 + i;
    float* orow = h_all + (size_t)gm2 * HID_SZ + n0 + tx * 8;
    const float* brow = b1 + n0 + tx * 8;
#pragma unroll
    for (int j = 0; j < 8; ++j) orow[j] = acc[i][j] + brow[j];
  }
}

// ---- LIF scan over T -------------------------------------------------------
__global__ __launch_bounds__(256) void lif_scan_kernel(
    const float* __restrict__ h_all, const float* __restrict__ Wo,
    const float* __restrict__ bo, float* __restrict__ out) {
  const int b = blockIdx.x;
  const int tid = threadIdx.x;
  float mem1[8];
  float wo0[8], wo1[8];
#pragma unroll
  for (int i = 0; i < 8; ++i) {
    mem1[i] = 0.f;
    wo0[i] = Wo[tid + 256 * i];
    wo1[i] = Wo[HID_SZ + tid + 256 * i];
  }
  __shared__ float partial[4][2];
  float memo0 = 0.f, memo1 = 0.f, acc0 = 0.f, acc1 = 0.f;
  const float bo0 = bo[0], bo1 = bo[1];
  for (int t = 0; t < T_STEPS; ++t) {
    const float* hrow = h_all + ((size_t)t * B_SZ + b) * HID_SZ;
    float p0 = 0.f, p1 = 0.f;
#pragma unroll
    for (int i = 0; i < 8; ++i) {
      float h = hrow[tid + 256 * i];
      float r1 = mem1[i] > 1.0f ? 1.0f : 0.0f;
      float m = 0.9f * mem1[i] + h - r1;
      mem1[i] = m;
      if (m > 1.0f) { p0 += wo0[i]; p1 += wo1[i]; }
    }
#pragma unroll
    for (int off = 32; off > 0; off >>= 1) {
      p0 += __shfl_down(p0, off);
      p1 += __shfl_down(p1, off);
    }
    const int wave = tid >> 6;
    if ((tid & 63) == 0) { partial[wave][0] = p0; partial[wave][1] = p1; }
    __syncthreads();
    if (tid == 0) {
      float o0 = partial[0][0] + partial[1][0] + partial[2][0] + partial[3][0] + bo0;
      float o1 = partial[0][1] + partial[1][1] + partial[2][1] + partial[3][1] + bo1;
      float ro0 = memo0 > 1.0f ? 1.0f : 0.0f;
      float ro1 = memo1 > 1.0f ? 1.0f : 0.0f;
      memo0 = 0.9f * memo0 + o0 - ro0;
      memo1 = 0.9f * memo1 + o1 - ro1;
      acc0 += memo0 > 1.0f ? 1.0f : 0.0f;
      acc1 += memo1 > 1.0f ? 1.0f : 0.0f;
    }
    __syncthreads();
  }
  if (tid == 0) {
    out[b * 2 + 0] = acc0;
    out[b * 2 + 1] = acc1;
  }
}

extern "C" void kernel_launch(void* const* d_in, const int* in_sizes, int n_in,
                              void* d_out, int out_size, void* d_ws, size_t ws_size,
                              hipStream_t stream) {
  const float* x  = (const float*)d_in[0];
  const float* W1 = (const float*)d_in[1];
  const float* b1 = (const float*)d_in[2];
  const float* Wo = (const float*)d_in[3];
  const float* bo = (const float*)d_in[4];
  float* out = (float*)d_out;

  const size_t hall_bytes = (size_t)T_STEPS * B_SZ * HID_SZ * 4;      // 26.2 MB
  const size_t a2_bytes = (size_t)T_STEPS * KSTEPS * CHUNK;           // 157.3 MB
  const size_t b2_bytes = (size_t)16 * KSTEPS * CHUNK;                // 100.7 MB
  char* ws = (char*)d_ws;
  float* h_all = (float*)ws;

  if (ws_size >= hall_bytes + a2_bytes + b2_bytes) {
    char* A2 = ws + hall_bytes;
    char* B2 = A2 + a2_bytes;
    conv_x_kernel<<<2048, 256, 0, stream>>>(x, A2);
    conv_w_kernel<<<2048, 256, 0, stream>>>(W1, B2);
    gemm_split_kernel<<<400, 256, 0, stream>>>(A2, B2, b1, h_all);
  } else {
    dim3 grid(25, 16);
    gemm_h_kernel<<<grid, 256, 0, stream>>>(x, W1, b1, h_all);
  }
  lif_scan_kernel<<<B_SZ, 256, 0, stream>>>(h_all, Wo, bo, out);
}

// Round 3
// 539.929 us; speedup vs baseline: 4.2877x; 1.1749x over previous
//
#include <hip/hip_runtime.h>

// SNN classifier: h_all = x @ W1^T + b1 via f16 split-2 MFMA (3 GEMM terms,
// fp32-grade accuracy), then sequential LIF scan over T=25.
//   x  [B=128, T=25, F=12288] f32 ; W1 [2048, 12288] ; Wo [2,2048]
// Split: x = Ah+Al (f16), W*128 = Bh+Bl (f16); h*128 = AhBh + AhBl + AlBh.
//
// GEMM: 256x128 tile, BK=32, 512 thr (8 waves 4Mx2N), counted-vmcnt pipeline:
//   LDS = A x3 buf (3*32KB) + B x2 buf (2*16KB) = 128KB, 1 block/CU.
//   A tile kt+2 and B tile kt+1 staged during tile kt; per-tile wait is
//   vmcnt(4) (B(kt+1)+everything older drained, A(kt+2)'s 4 stay in flight),
//   raw s_barrier + sched_barrier(0); 2 phases/tile, setprio around MFMA.
// LDS image is [k-slot 0..7][row][16B] (hi slots 0-3, lo 4-7): ds_read_b128
// is 16-lane contiguous -> conflict-free. Conversion kernels pre-write this
// exact image so global_load_lds stays linear (guide rule #21).

#define T_STEPS 25
#define B_SZ    128
#define F_SZ    12288
#define HID_SZ  2048
#define KT      384            // F / 32
#define A_CH    32768          // 256 rows * 32k * 4B(f16 hi+lo)
#define B_CH    16384          // 128 rows * 32k * 4B
#define M_PAD   3328           // 13 * 256

typedef __attribute__((ext_vector_type(8))) _Float16 f16x8;
typedef __attribute__((ext_vector_type(4))) float f32x4;

__device__ __forceinline__ void g2l16(const void* g, void* l) {
  __builtin_amdgcn_global_load_lds(
      (const __attribute__((address_space(1))) void*)g,
      (__attribute__((address_space(3))) void*)l, 16, 0, 0);
}

// ---- conversion: x -> A2 [mt][ks][slot][r][16B] ----------------------------
__global__ __launch_bounds__(256) void conv_x_kernel(
    const float* __restrict__ x, char* __restrict__ A2) {
  const int total = 13 * KT * 256 * 4;  // (mt,ks,r,s)
  for (int i = blockIdx.x * 256 + threadIdx.x; i < total; i += gridDim.x * 256) {
    const int s = i & 3;
    const int r = (i >> 2) & 255;
    const int rest = i >> 10;            // mt*KT + ks
    const int ks = rest % KT;
    const int mt = rest / KT;
    const int m = mt * 256 + r;          // padded row
    const int b = m & 127;
    const int t = m >> 7;
    f16x8 hi = {0, 0, 0, 0, 0, 0, 0, 0};
    f16x8 lo = {0, 0, 0, 0, 0, 0, 0, 0};
    if (t < T_STEPS) {
      const float* src = x + ((size_t)(b * T_STEPS + t)) * F_SZ + ks * 32 + s * 8;
      float4 v0 = *(const float4*)src;
      float4 v1 = *(const float4*)(src + 4);
      float vf[8] = {v0.x, v0.y, v0.z, v0.w, v1.x, v1.y, v1.z, v1.w};
#pragma unroll
      for (int j = 0; j < 8; ++j) {
        _Float16 h = (_Float16)vf[j];
        hi[j] = h;
        lo[j] = (_Float16)(vf[j] - (float)h);
      }
    }
    char* chunk = A2 + (size_t)rest * A_CH;
    *(f16x8*)(chunk + s * 4096 + r * 16) = hi;          // slots 0-3: hi
    *(f16x8*)(chunk + (s + 4) * 4096 + r * 16) = lo;    // slots 4-7: lo
  }
}

// ---- conversion: W1*128 -> B2 [nt][ks][slot][r][16B] -----------------------
__global__ __launch_bounds__(256) void conv_w_kernel(
    const float* __restrict__ W1, char* __restrict__ B2) {
  const int total = 16 * KT * 128 * 4;
  for (int i = blockIdx.x * 256 + threadIdx.x; i < total; i += gridDim.x * 256) {
    const int s = i & 3;
    const int r = (i >> 2) & 127;
    const int rest = i >> 9;             // nt*KT + ks
    const int ks = rest % KT;
    const int nt = rest / KT;
    const float* src = W1 + ((size_t)(nt * 128 + r)) * F_SZ + ks * 32 + s * 8;
    float4 v0 = *(const float4*)src;
    float4 v1 = *(const float4*)(src + 4);
    float vf[8] = {v0.x, v0.y, v0.z, v0.w, v1.x, v1.y, v1.z, v1.w};
    f16x8 hi, lo;
#pragma unroll
    for (int j = 0; j < 8; ++j) {
      float vs = vf[j] * 128.0f;         // scale keeps residual f16-normal
      _Float16 h = (_Float16)vs;
      hi[j] = h;
      lo[j] = (_Float16)(vs - (float)h);
    }
    char* chunk = B2 + (size_t)rest * B_CH;
    *(f16x8*)(chunk + s * 2048 + r * 16) = hi;
    *(f16x8*)(chunk + (s + 4) * 2048 + r * 16) = lo;
  }
}

// ---- MFMA GEMM with counted-vmcnt pipeline ---------------------------------
__global__ __launch_bounds__(512) void gemm_mfma_kernel(
    const char* __restrict__ A2, const char* __restrict__ B2,
    const float* __restrict__ b1, float* __restrict__ h_all) {
  // LDS: A bufs 0..2 at k*32768 ; B bufs 0..1 at 98304 + k*16384
  __shared__ __align__(16) char lds[131072];
  const int tid = threadIdx.x;
  const int l = tid & 63;
  const int w = tid >> 6;      // wave 0..7
  const int wm = w >> 1;       // 0..3 : rows wm*64..+64
  const int wn = w & 1;        // 0..1 : cols wn*64..+64

  // XCD-aware bijective swizzle (208 = 8 XCDs * 26)
  const int bid = blockIdx.x;
  const int swz = (bid & 7) * 26 + (bid >> 3);
  const int mt = swz >> 4;     // 0..12
  const int nt = swz & 15;     // 0..15
  const char* aSrc = A2 + (size_t)mt * KT * A_CH;
  const char* bSrc = B2 + (size_t)nt * KT * B_CH;

#define STAGE_A_PAIR(ktx, i0)                                              \
  do {                                                                     \
    const char* s_ = aSrc + (size_t)(ktx) * A_CH + (i0) * 8192 + tid * 16; \
    char* d_ = (char*)lds + ((ktx) % 3) * 32768 + (i0) * 8192 + w * 1024;  \
    g2l16(s_, d_);                                                         \
    g2l16(s_ + 8192, d_ + 8192);                                           \
  } while (0)
#define STAGE_B2(ktx)                                                      \
  do {                                                                     \
    const char* s_ = bSrc + (size_t)(ktx) * B_CH + tid * 16;               \
    char* d_ = (char*)lds + 98304 + ((ktx) & 1) * 16384 + w * 1024;        \
    g2l16(s_, d_);                                                         \
    g2l16(s_ + 8192, d_ + 8192);                                           \
  } while (0)

  f32x4 acc[4][4];
#pragma unroll
  for (int i = 0; i < 4; ++i)
#pragma unroll
    for (int j = 0; j < 4; ++j) acc[i][j] = (f32x4){0.f, 0.f, 0.f, 0.f};

  // fragment LDS offsets: slot = l>>4 (k = slot*8..+8), row = base + (l&15)
  const int aoff = (l >> 4) * 4096 + (wm * 64 + (l & 15)) * 16;
  const int boff = (l >> 4) * 2048 + (wn * 64 + (l & 15)) * 16;

  // prologue: A(0) x4, B(0) x2, A(1) x4, B(1) x2  (issue order matters)
  STAGE_A_PAIR(0, 0); STAGE_A_PAIR(0, 2); STAGE_B2(0);
  STAGE_A_PAIR(1, 0); STAGE_A_PAIR(1, 2); STAGE_B2(1);

#define MM3(mf, nf, AH, AL, BH, BL)                                                      \
  acc[mf][nf] = __builtin_amdgcn_mfma_f32_16x16x32_f16(AH, BH, acc[mf][nf], 0, 0, 0);    \
  acc[mf][nf] = __builtin_amdgcn_mfma_f32_16x16x32_f16(AH, BL, acc[mf][nf], 0, 0, 0);    \
  acc[mf][nf] = __builtin_amdgcn_mfma_f32_16x16x32_f16(AL, BH, acc[mf][nf], 0, 0, 0);

  for (int kt = 0; kt < KT; ++kt) {
    // tile-start wait: drain up to this tile's loads, keep newer in flight
    if (kt == 0) {
      asm volatile("s_waitcnt vmcnt(6)" ::: "memory");
    } else if (kt < KT - 1) {
      asm volatile("s_waitcnt vmcnt(4)" ::: "memory");
    } else {
      asm volatile("s_waitcnt vmcnt(0)" ::: "memory");
    }
    __builtin_amdgcn_s_barrier();
    asm volatile("" ::: "memory");
    __builtin_amdgcn_sched_barrier(0);

    const char* la = (const char*)lds + (kt % 3) * 32768;
    const char* lb = (const char*)lds + 98304 + (kt & 1) * 16384;

    // ---- phase A: all A frags + B nf0,1 ----
    f16x8 ah0 = *(const f16x8*)(la + aoff);
    f16x8 ah1 = *(const f16x8*)(la + aoff + 256);
    f16x8 ah2 = *(const f16x8*)(la + aoff + 512);
    f16x8 ah3 = *(const f16x8*)(la + aoff + 768);
    f16x8 al0 = *(const f16x8*)(la + aoff + 16384);
    f16x8 al1 = *(const f16x8*)(la + aoff + 16384 + 256);
    f16x8 al2 = *(const f16x8*)(la + aoff + 16384 + 512);
    f16x8 al3 = *(const f16x8*)(la + aoff + 16384 + 768);
    f16x8 bh0 = *(const f16x8*)(lb + boff);
    f16x8 bl0 = *(const f16x8*)(lb + boff + 8192);
    f16x8 bh1 = *(const f16x8*)(lb + boff + 256);
    f16x8 bl1 = *(const f16x8*)(lb + boff + 8192 + 256);

    if (kt >= 1 && kt <= KT - 2) STAGE_B2(kt + 1);   // B(1) staged in prologue
    if (kt <= KT - 3) STAGE_A_PAIR(kt + 2, 0);

    __builtin_amdgcn_s_setprio(1);
    MM3(0, 0, ah0, al0, bh0, bl0)
    MM3(1, 0, ah1, al1, bh0, bl0)
    MM3(2, 0, ah2, al2, bh0, bl0)
    MM3(3, 0, ah3, al3, bh0, bl0)
    MM3(0, 1, ah0, al0, bh1, bl1)
    MM3(1, 1, ah1, al1, bh1, bl1)
    MM3(2, 1, ah2, al2, bh1, bl1)
    MM3(3, 1, ah3, al3, bh1, bl1)
    __builtin_amdgcn_s_setprio(0);

    __builtin_amdgcn_s_barrier();   // mid-tile lockstep barrier (no drain)

    // ---- phase B: B nf2,3 (A frags reused) ----
    f16x8 bh2 = *(const f16x8*)(lb + boff + 512);
    f16x8 bl2 = *(const f16x8*)(lb + boff + 8192 + 512);
    f16x8 bh3 = *(const f16x8*)(lb + boff + 768);
    f16x8 bl3 = *(const f16x8*)(lb + boff + 8192 + 768);

    if (kt <= KT - 3) STAGE_A_PAIR(kt + 2, 2);

    __builtin_amdgcn_s_setprio(1);
    MM3(0, 2, ah0, al0, bh2, bl2)
    MM3(1, 2, ah1, al1, bh2, bl2)
    MM3(2, 2, ah2, al2, bh2, bl2)
    MM3(3, 2, ah3, al3, bh2, bl2)
    MM3(0, 3, ah0, al0, bh3, bl3)
    MM3(1, 3, ah1, al1, bh3, bl3)
    MM3(2, 3, ah2, al2, bh3, bl3)
    MM3(3, 3, ah3, al3, bh3, bl3)
    __builtin_amdgcn_s_setprio(0);
  }

  // epilogue: h = acc/128 + b1.  C/D frag: col=lane&15, row=(lane>>4)*4+q
  const int row0 = mt * 256 + wm * 64 + (l >> 4) * 4;
  const int col0 = nt * 128 + wn * 64 + (l & 15);
#pragma unroll
  for (int nf = 0; nf < 4; ++nf) {
    const int col = col0 + nf * 16;
    const float bias = b1[col];
#pragma unroll
    for (int mf = 0; mf < 4; ++mf) {
#pragma unroll
      for (int q = 0; q < 4; ++q) {
        const int row = row0 + mf * 16 + q;
        h_all[(size_t)row * HID_SZ + col] = acc[mf][nf][q] * 0.0078125f + bias;
      }
    }
  }
#undef STAGE_A_PAIR
#undef STAGE_B2
#undef MM3
}

// ---- fallback fp32 vector GEMM (used only if ws too small) -----------------
__global__ __launch_bounds__(256) void gemm_h_kernel(
    const float* __restrict__ x, const float* __restrict__ W1,
    const float* __restrict__ b1, float* __restrict__ h_all) {
  __shared__ float As[16][128];
  __shared__ float Bs[16][128];
  const int tid = threadIdx.x;
  const int tx = tid & 15;
  const int ty = tid >> 4;
  const int m0 = blockIdx.x * 128;
  const int n0 = blockIdx.y * 128;
  const int lrow = tid >> 1;
  const int lcol = (tid & 1) * 8;
  const int gm = m0 + lrow;
  const int bb = gm & (B_SZ - 1);
  const int tt = gm >> 7;
  const float* aptr = x + ((size_t)bb * T_STEPS + tt) * F_SZ + lcol;
  const float* bptr = W1 + (size_t)(n0 + lrow) * F_SZ + lcol;
  float acc[8][8];
#pragma unroll
  for (int i = 0; i < 8; ++i)
#pragma unroll
    for (int j = 0; j < 8; ++j) acc[i][j] = 0.f;
  for (int k0 = 0; k0 < F_SZ; k0 += 16) {
    float4 av0 = *(const float4*)(aptr + k0);
    float4 av1 = *(const float4*)(aptr + k0 + 4);
    float4 bv0 = *(const float4*)(bptr + k0);
    float4 bv1 = *(const float4*)(bptr + k0 + 4);
    As[lcol + 0][lrow] = av0.x; As[lcol + 1][lrow] = av0.y;
    As[lcol + 2][lrow] = av0.z; As[lcol + 3][lrow] = av0.w;
    As[lcol + 4][lrow] = av1.x; As[lcol + 5][lrow] = av1.y;
    As[lcol + 6][lrow] = av1.z; As[lcol + 7][lrow] = av1.w;
    Bs[lcol + 0][lrow] = bv0.x; Bs[lcol + 1][lrow] = bv0.y;
    Bs[lcol + 2][lrow] = bv0.z; Bs[lcol + 3][lrow] = bv0.w;
    Bs[lcol + 4][lrow] = bv1.x; Bs[lcol + 5][lrow] = bv1.y;
    Bs[lcol + 6][lrow] = bv1.z; Bs[lcol + 7][lrow] = bv1.w;
    __syncthreads();
#pragma unroll
    for (int k = 0; k < 16; ++k) {
      float4 a0 = *(const float4*)&As[k][ty * 8];
      float4 a1 = *(const float4*)&As[k][ty * 8 + 4];
      float4 q0 = *(const float4*)&Bs[k][tx * 8];
      float4 q1 = *(const float4*)&Bs[k][tx * 8 + 4];
      float ar[8] = {a0.x, a0.y, a0.z, a0.w, a1.x, a1.y, a1.z, a1.w};
      float br[8] = {q0.x, q0.y, q0.z, q0.w, q1.x, q1.y, q1.z, q1.w};
#pragma unroll
      for (int i = 0; i < 8; ++i)
#pragma unroll
        for (int j = 0; j < 8; ++j)
          acc[i][j] = fmaf(ar[i], br[j], acc[i][j]);
    }
    __syncthreads();
  }
#pragma unroll
  for (int i = 0; i < 8; ++i) {
    const int gm2 = m0 + ty * 8 + i;
    float* orow = h_all + (size_t)gm2 * HID_SZ + n0 + tx * 8;
    const float* brow = b1 + n0 + tx * 8;
#pragma unroll
    for (int j = 0; j < 8; ++j) orow[j] = acc[i][j] + brow[j];
  }
}

// ---- LIF scan over T -------------------------------------------------------
__global__ __launch_bounds__(256) void lif_scan_kernel(
    const float* __restrict__ h_all, const float* __restrict__ Wo,
    const float* __restrict__ bo, float* __restrict__ out) {
  const int b = blockIdx.x;
  const int tid = threadIdx.x;
  float mem1[8];
  float wo0[8], wo1[8];
#pragma unroll
  for (int i = 0; i < 8; ++i) {
    mem1[i] = 0.f;
    wo0[i] = Wo[tid + 256 * i];
    wo1[i] = Wo[HID_SZ + tid + 256 * i];
  }
  __shared__ float partial[4][2];
  float memo0 = 0.f, memo1 = 0.f, acc0 = 0.f, acc1 = 0.f;
  const float bo0 = bo[0], bo1 = bo[1];
  for (int t = 0; t < T_STEPS; ++t) {
    const float* hrow = h_all + ((size_t)t * B_SZ + b) * HID_SZ;
    float p0 = 0.f, p1 = 0.f;
#pragma unroll
    for (int i = 0; i < 8; ++i) {
      float h = hrow[tid + 256 * i];
      float r1 = mem1[i] > 1.0f ? 1.0f : 0.0f;
      float m = 0.9f * mem1[i] + h - r1;
      mem1[i] = m;
      if (m > 1.0f) { p0 += wo0[i]; p1 += wo1[i]; }
    }
#pragma unroll
    for (int off = 32; off > 0; off >>= 1) {
      p0 += __shfl_down(p0, off);
      p1 += __shfl_down(p1, off);
    }
    const int wave = tid >> 6;
    if ((tid & 63) == 0) { partial[wave][0] = p0; partial[wave][1] = p1; }
    __syncthreads();
    if (tid == 0) {
      float o0 = partial[0][0] + partial[1][0] + partial[2][0] + partial[3][0] + bo0;
      float o1 = partial[0][1] + partial[1][1] + partial[2][1] + partial[3][1] + bo1;
      float ro0 = memo0 > 1.0f ? 1.0f : 0.0f;
      float ro1 = memo1 > 1.0f ? 1.0f : 0.0f;
      memo0 = 0.9f * memo0 + o0 - ro0;
      memo1 = 0.9f * memo1 + o1 - ro1;
      acc0 += memo0 > 1.0f ? 1.0f : 0.0f;
      acc1 += memo1 > 1.0f ? 1.0f : 0.0f;
    }
    __syncthreads();
  }
  if (tid == 0) {
    out[b * 2 + 0] = acc0;
    out[b * 2 + 1] = acc1;
  }
}

extern "C" void kernel_launch(void* const* d_in, const int* in_sizes, int n_in,
                              void* d_out, int out_size, void* d_ws, size_t ws_size,
                              hipStream_t stream) {
  const float* x  = (const float*)d_in[0];
  const float* W1 = (const float*)d_in[1];
  const float* b1 = (const float*)d_in[2];
  const float* Wo = (const float*)d_in[3];
  const float* bo = (const float*)d_in[4];
  float* out = (float*)d_out;

  const size_t hall_bytes = (size_t)M_PAD * HID_SZ * 4;        // 27.26 MB
  const size_t a2_bytes = (size_t)13 * KT * A_CH;              // 163.6 MB
  const size_t b2_bytes = (size_t)16 * KT * B_CH;              // 100.7 MB
  char* ws = (char*)d_ws;
  float* h_all = (float*)ws;

  if (ws_size >= hall_bytes + a2_bytes + b2_bytes) {
    char* A2 = ws + hall_bytes;
    char* B2 = A2 + a2_bytes;
    conv_x_kernel<<<2048, 256, 0, stream>>>(x, A2);
    conv_w_kernel<<<2048, 256, 0, stream>>>(W1, B2);
    gemm_mfma_kernel<<<208, 512, 0, stream>>>(A2, B2, b1, h_all);
  } else {
    dim3 grid(25, 16);
    gemm_h_kernel<<<grid, 256, 0, stream>>>(x, W1, b1, h_all);
  }
  lif_scan_kernel<<<B_SZ, 256, 0, stream>>>(h_all, Wo, bo, out);
}